// Round 4
// baseline (129.747 us; speedup 1.0000x reference)
//
#include <hip/hip_runtime.h>
#include <math.h>

typedef float v2f __attribute__((ext_vector_type(2)));

#define TPB 256   // threads per block
#define IPT 4     // "self" rows per thread (registers)
#define JS  64    // j-slices per direction (split-K over the other cloud)

// ---------------------------------------------------------------------------
// Kernel 1 (fused setup): transform src, repack BOTH clouds as SoA
// (x[], y[], z[], w[]=|v|^2), init pack arrays to u64-max, zero the output
// accumulator, +INF sentinel pads for the 2-wide tail reads.
// ---------------------------------------------------------------------------
__global__ __launch_bounds__(256) void setup_kernel(
    const float* __restrict__ ref, const float* __restrict__ src,
    const float* __restrict__ T,
    float* __restrict__ rx, float* __restrict__ ry, float* __restrict__ rz,
    float* __restrict__ rw,
    float* __restrict__ sx, float* __restrict__ sy, float* __restrict__ sz,
    float* __restrict__ sw,
    unsigned long long* __restrict__ packF,
    unsigned long long* __restrict__ packB,
    float* __restrict__ out, int N, int M) {
  int i = blockIdx.x * blockDim.x + threadIdx.x;
  if (i < M) {
    float x = src[3 * i], y = src[3 * i + 1], z = src[3 * i + 2];
    float tx = T[0] * x + T[1] * y + T[2]  * z + T[3];
    float ty = T[4] * x + T[5] * y + T[6]  * z + T[7];
    float tz = T[8] * x + T[9] * y + T[10] * z + T[11];
    sx[i] = tx; sy[i] = ty; sz[i] = tz;
    sw[i] = tx * tx + ty * ty + tz * tz;
    packB[i] = ~0ull;
  }
  if (i < N) {
    float x = ref[3 * i], y = ref[3 * i + 1], z = ref[3 * i + 2];
    rx[i] = x; ry[i] = y; rz[i] = z;
    rw[i] = x * x + y * y + z * z;
    packF[i] = ~0ull;
  }
  if (i == 0) {
    out[0] = 0.0f;
    rx[N] = 0.f; ry[N] = 0.f; rz[N] = 0.f; rw[N] = INFINITY;  // pad sentinel
    sx[M] = 0.f; sy[M] = 0.f; sz[M] = 0.f; sw[M] = INFINITY;  // pad sentinel
  }
}

__device__ __forceinline__ unsigned int sortable(float f) {
  unsigned int u = __float_as_uint(f);
  return u ^ ((unsigned int)((int)u >> 31) | 0x80000000u);
}

// ---------------------------------------------------------------------------
// Kernel 2 (phase 1): per-(row, chunk) MIN of score_j = |q_j|^2 - 2 p.q_j
// -- value only, NO index tracking:
//   per 2 j's per row: 3 v_pk_fma_f32 + 1 v_min3_f32 = 2.0 VALU/pair.
// Partials merged via packed-u64 atomicMin:
//   key = (sortable score bits << 32) | chunk_base_j0
// Ties pick the smallest chunk -> combined with phase 2's smallest-matching-j
// scan this reproduces jnp.argmin first-occurrence semantics exactly.
// ---------------------------------------------------------------------------
__global__ __launch_bounds__(TPB) void pairs_kernel(
    const float* __restrict__ rx, const float* __restrict__ ry,
    const float* __restrict__ rz, const float* __restrict__ rw,
    const float* __restrict__ sx, const float* __restrict__ sy,
    const float* __restrict__ sz, const float* __restrict__ sw,
    unsigned long long* __restrict__ packF,
    unsigned long long* __restrict__ packB,
    int N, int M, int nbF) {
  int b = blockIdx.x;
  const float *px_, *py_, *pz_, *ox, *oy, *oz, *ow;
  unsigned long long* pack;
  int selfN, otherN;
  if (b < nbF) {  // forward: self = ref, other = transformed src
    px_ = rx; py_ = ry; pz_ = rz;
    ox = sx; oy = sy; oz = sz; ow = sw;
    pack = packF; selfN = N; otherN = M;
  } else {        // backward: self = transformed src, other = ref
    b -= nbF;
    px_ = sx; py_ = sy; pz_ = sz;
    ox = rx; oy = ry; oz = rz; ow = rw;
    pack = packB; selfN = M; otherN = N;
  }
  const int ib = b / JS, jb = b % JS;
  const int i0 = ib * (TPB * IPT) + threadIdx.x;

  float ax[IPT], ay[IPT], az[IPT], mind[IPT];
#pragma unroll
  for (int k = 0; k < IPT; k++) {
    int i = i0 + k * TPB;
    int ic = (i < selfN) ? i : (selfN - 1);  // clamp; guarded at atomic time
    ax[k] = -2.0f * px_[ic]; ay[k] = -2.0f * py_[ic]; az[k] = -2.0f * pz_[ic];
    mind[k] = INFINITY;
  }

  int chunk = (otherN + JS - 1) / JS;
  chunk = (chunk + 1) & ~1;  // even -> 8B-aligned v2f loads
  const int j0 = jb * chunk;
  const int jcount = min(chunk, otherN - j0);  // may be <= 0

#pragma unroll 4
  for (int jj = 0; jj < jcount; jj += 2) {
    v2f qx = *(const v2f*)(ox + j0 + jj);  // wave-uniform broadcast loads
    v2f qy = *(const v2f*)(oy + j0 + jj);
    v2f qz = *(const v2f*)(oz + j0 + jj);
    v2f qw = *(const v2f*)(ow + j0 + jj);
#pragma unroll
    for (int k = 0; k < IPT; k++) {
      v2f t = __builtin_elementwise_fma((v2f){ax[k], ax[k]}, qx, qw);
      t = __builtin_elementwise_fma((v2f){ay[k], ay[k]}, qy, t);
      t = __builtin_elementwise_fma((v2f){az[k], az[k]}, qz, t);
      mind[k] = fminf(fminf(t.x, t.y), mind[k]);  // v_min3_f32
    }
  }

#pragma unroll
  for (int k = 0; k < IPT; k++) {
    int i = i0 + k * TPB;
    if (i < selfN && jcount > 0) {
      unsigned long long p = ((unsigned long long)sortable(mind[k]) << 32) |
                             (unsigned int)j0;
      atomicMin(&pack[i], p);
    }
  }
}

// ---------------------------------------------------------------------------
// Kernel 3 (phase 2 + epilogue): ONE WAVE PER ROW. Rescan only the winning
// chunk (coalesced, lane-per-j), recompute scores with the identical fma
// sequence (bitwise-equal), find the smallest j matching the winning score,
// then exact distance + sigma gather + log + mean; block-reduce + atomicAdd.
// ---------------------------------------------------------------------------
__global__ __launch_bounds__(256) void finalize_kernel(
    const unsigned long long* __restrict__ packF,
    const unsigned long long* __restrict__ packB,
    const float* __restrict__ rx, const float* __restrict__ ry,
    const float* __restrict__ rz,
    const float* __restrict__ sx, const float* __restrict__ sy,
    const float* __restrict__ sz,
    const float* __restrict__ ref_sigma, const float* __restrict__ src_sigma,
    float* __restrict__ out, int N, int M) {
  const int lane = threadIdx.x & 63, wid = threadIdx.x >> 6;
  const int gw = blockIdx.x * (blockDim.x >> 6) + wid;  // global wave id
  float term = 0.f;
  if (gw < N + M) {
    const bool fwd = (gw < N);
    const int row = fwd ? gw : gw - N;
    const float *px_, *py_, *pz_, *ox, *oy, *oz, *sigA, *sigB;
    int otherN, selfN;
    const unsigned long long* pack;
    if (fwd) {
      px_ = rx; py_ = ry; pz_ = rz; ox = sx; oy = sy; oz = sz;
      sigA = ref_sigma; sigB = src_sigma; pack = packF;
      selfN = N; otherN = M;
    } else {
      px_ = sx; py_ = sy; pz_ = sz; ox = rx; oy = ry; oz = rz;
      sigA = src_sigma; sigB = ref_sigma; pack = packB;
      selfN = M; otherN = N;
    }
    const unsigned long long key = pack[row];
    const unsigned int target = (unsigned int)(key >> 32);
    const int j0 = (int)(key & 0xffffffffu);
    int chunk = (otherN + JS - 1) / JS;
    chunk = (chunk + 1) & ~1;
    const int jc = min(chunk, otherN - j0);
    const int jc2 = (jc + 1) & ~1;  // phase-1 scanned [j0, j0+jc2)

    const float px = px_[row], py = py_[row], pz = pz_[row];
    const float ax = -2.0f * px, ay = -2.0f * py, az = -2.0f * pz;
    // note: ow[j] == ox^2+oy^2+oz^2 recomputed == stored value? It was
    // STORED; reuse the stored array for bitwise match:
    const float* ow = fwd ? (sx ? nullptr : nullptr) : nullptr;  // unused
    (void)ow;

    int best = 0x7fffffff;
    for (int off = lane; off < jc2; off += 64) {
      const int j = j0 + off;
      // |q|^2 must be the SAME value phase 1 used -> read the stored w array
      const float qw = fwd ? ((const float*)oz)[0] : 0.f;  // placeholder
      (void)qw;
      // (w arrays passed via oz+? -- see real impl below)
      best = best;  // replaced below
      break;
    }
    // ---- real scan (w arrays threaded through explicitly) ----
    const float* oww = fwd ? (const float*)(oz + 0) : (const float*)(oz + 0);
    (void)oww;
    best = 0x7fffffff;
    // We re-derive the w pointer from the known SoA layout: the caller passes
    // rz/sz such that rw = rz + (rw-rz) ... instead, scan recomputing w from
    // coords is NOT bitwise-safe. The w arrays are passed as extra args:
    // (see signature change below -- rw_, sw_)
    // -- this block is replaced by the code in finalize_kernel2 --
    term = 0.f;
  }
  (void)term;
}

// Clean implementation with w arrays in the signature.
__global__ __launch_bounds__(256) void finalize2_kernel(
    const unsigned long long* __restrict__ packF,
    const unsigned long long* __restrict__ packB,
    const float* __restrict__ rx, const float* __restrict__ ry,
    const float* __restrict__ rz, const float* __restrict__ rw,
    const float* __restrict__ sx, const float* __restrict__ sy,
    const float* __restrict__ sz, const float* __restrict__ sw,
    const float* __restrict__ ref_sigma, const float* __restrict__ src_sigma,
    float* __restrict__ out, int N, int M) {
  const int lane = threadIdx.x & 63, wid = threadIdx.x >> 6;
  const int gw = blockIdx.x * (blockDim.x >> 6) + wid;  // global wave id
  float term = 0.f;
  if (gw < N + M) {
    const bool fwd = (gw < N);
    const int row = fwd ? gw : gw - N;
    const float *px_, *py_, *pz_, *ox, *oy, *oz, *ow, *sigA, *sigB;
    int otherN;
    const unsigned long long* pack;
    if (fwd) {
      px_ = rx; py_ = ry; pz_ = rz; ox = sx; oy = sy; oz = sz; ow = sw;
      sigA = ref_sigma; sigB = src_sigma; pack = packF; otherN = M;
    } else {
      px_ = sx; py_ = sy; pz_ = sz; ox = rx; oy = ry; oz = rz; ow = rw;
      sigA = src_sigma; sigB = ref_sigma; pack = packB; otherN = N;
    }
    const unsigned long long key = pack[row];
    const unsigned int target = (unsigned int)(key >> 32);
    const int j0 = (int)(key & 0xffffffffu);
    int chunk = (otherN + JS - 1) / JS;
    chunk = (chunk + 1) & ~1;
    const int jc = min(chunk, otherN - j0);
    const int jc2 = (jc + 1) & ~1;  // phase-1 scanned exactly [j0, j0+jc2)

    const float px = px_[row], py = py_[row], pz = pz_[row];
    const float ax = -2.0f * px, ay = -2.0f * py, az = -2.0f * pz;

    int best = 0x7fffffff;
    for (int off = lane; off < jc2; off += 64) {
      const int j = j0 + off;
      float t = fmaf(ax, ox[j], ow[j]);
      t = fmaf(ay, oy[j], t);
      t = fmaf(az, oz[j], t);
      if (sortable(t) == target) best = min(best, j);
    }
#pragma unroll
    for (int o = 32; o > 0; o >>= 1) best = min(best, __shfl_down(best, o, 64));
    best = __shfl(best, 0, 64);

    const float dx = px - ox[best], dy = py - oy[best], dz = pz - oz[best];
    const float d = sqrtf(dx * dx + dy * dy + dz * dz);
    const float sigma = 0.5f * (sigA[row] + sigB[best]);
    if (lane == 0)
      term = (logf(sigma) + d / sigma) * (fwd ? 1.0f / (float)N
                                             : 1.0f / (float)M);
  }
  __shared__ float wsum[4];
  if (lane == 0) wsum[wid] = term;
  __syncthreads();
  if (threadIdx.x == 0) {
    float s = wsum[0] + wsum[1] + wsum[2] + wsum[3];
    atomicAdd(out, s);
  }
}

extern "C" void kernel_launch(void* const* d_in, const int* in_sizes, int n_in,
                              void* d_out, int out_size, void* d_ws,
                              size_t ws_size, hipStream_t stream) {
  const float* ref_kpts  = (const float*)d_in[0];
  const float* src_kpts  = (const float*)d_in[1];
  const float* gt        = (const float*)d_in[2];
  const float* ref_sigma = (const float*)d_in[3];
  const float* src_sigma = (const float*)d_in[4];
  float* out = (float*)d_out;

  const int N = in_sizes[0] / 3;
  const int M = in_sizes[1] / 3;

  // workspace layout (SoA, each array padded +1 sentinel, stride rounded to
  // 4 floats so every array base stays 16B-aligned)
  const int NP = (N + 1 + 3) & ~3;
  const int MP = (M + 1 + 3) & ~3;
  float* f = (float*)d_ws;
  float* rx = f;            float* ry = f + NP;
  float* rz = f + 2 * NP;   float* rw = f + 3 * NP;
  float* sx = f + 4 * NP;           float* sy = f + 4 * NP + MP;
  float* sz = f + 4 * NP + 2 * MP;  float* sw = f + 4 * NP + 3 * MP;
  unsigned long long* packF = (unsigned long long*)(f + 4 * NP + 4 * MP);
  unsigned long long* packB = packF + N;

  int nPts = (N > M) ? N : M;
  setup_kernel<<<(nPts + 255) / 256, 256, 0, stream>>>(
      ref_kpts, src_kpts, gt, rx, ry, rz, rw, sx, sy, sz, sw, packF, packB,
      out, N, M);

  const int ibF = (N + TPB * IPT - 1) / (TPB * IPT);  // row-blocks (forward)
  const int ibB = (M + TPB * IPT - 1) / (TPB * IPT);  // row-blocks (backward)
  const int nbF = ibF * JS;
  const int nbB = ibB * JS;
  pairs_kernel<<<nbF + nbB, TPB, 0, stream>>>(rx, ry, rz, rw, sx, sy, sz, sw,
                                              packF, packB, N, M, nbF);

  const int waves = N + M;                 // one wave per row
  const int wpb = 256 / 64;                // waves per block
  finalize2_kernel<<<(waves + wpb - 1) / wpb, 256, 0, stream>>>(
      packF, packB, rx, ry, rz, rw, sx, sy, sz, sw, ref_sigma, src_sigma, out,
      N, M);
}

// Round 5
// 97.763 us; speedup vs baseline: 1.3272x; 1.3272x over previous
//
#include <hip/hip_runtime.h>
#include <math.h>

typedef float v2f __attribute__((ext_vector_type(2)));

#define TPB 256   // threads per block
#define IPT 4     // "self" rows per thread (registers)
#define JS  64    // j-slices per direction (split-K over the other cloud)

// ---------------------------------------------------------------------------
// Kernel 1 (fused setup): transform src, repack BOTH clouds as SoA
// (x[], y[], z[], w[]=|v|^2), init pack arrays to u64-max, +INF sentinel
// pads for the 2-wide tail reads.
// ---------------------------------------------------------------------------
__global__ __launch_bounds__(256) void setup_kernel(
    const float* __restrict__ ref, const float* __restrict__ src,
    const float* __restrict__ T,
    float* __restrict__ rx, float* __restrict__ ry, float* __restrict__ rz,
    float* __restrict__ rw,
    float* __restrict__ sx, float* __restrict__ sy, float* __restrict__ sz,
    float* __restrict__ sw,
    unsigned long long* __restrict__ packF,
    unsigned long long* __restrict__ packB, int N, int M) {
  int i = blockIdx.x * blockDim.x + threadIdx.x;
  if (i < M) {
    float x = src[3 * i], y = src[3 * i + 1], z = src[3 * i + 2];
    float tx = T[0] * x + T[1] * y + T[2]  * z + T[3];
    float ty = T[4] * x + T[5] * y + T[6]  * z + T[7];
    float tz = T[8] * x + T[9] * y + T[10] * z + T[11];
    sx[i] = tx; sy[i] = ty; sz[i] = tz;
    sw[i] = tx * tx + ty * ty + tz * tz;
    packB[i] = ~0ull;
  }
  if (i < N) {
    float x = ref[3 * i], y = ref[3 * i + 1], z = ref[3 * i + 2];
    rx[i] = x; ry[i] = y; rz[i] = z;
    rw[i] = x * x + y * y + z * z;
    packF[i] = ~0ull;
  }
  if (i == 0) {
    rx[N] = 0.f; ry[N] = 0.f; rz[N] = 0.f; rw[N] = INFINITY;  // pad sentinel
    sx[M] = 0.f; sy[M] = 0.f; sz[M] = 0.f; sw[M] = INFINITY;  // pad sentinel
  }
}

__device__ __forceinline__ unsigned int sortable(float f) {
  unsigned int u = __float_as_uint(f);
  return u ^ ((unsigned int)((int)u >> 31) | 0x80000000u);
}

// ---------------------------------------------------------------------------
// Kernel 2 (phase 1): per-(row, chunk) MIN of score_j = |q_j|^2 - 2 p.q_j
// -- value only, NO index tracking:
//   per 2 j's per row: 3 v_pk_fma_f32 + 1 v_min3_f32 = 2.0 VALU/pair.
// Partials merged via packed-u64 atomicMin (distinct address per row):
//   key = (sortable score bits << 32) | chunk_base_j0
// Ties pick the smallest chunk -> with phase 2's smallest-matching-j scan
// this reproduces jnp.argmin first-occurrence semantics exactly.
// ---------------------------------------------------------------------------
__global__ __launch_bounds__(TPB) void pairs_kernel(
    const float* __restrict__ rx, const float* __restrict__ ry,
    const float* __restrict__ rz, const float* __restrict__ rw,
    const float* __restrict__ sx, const float* __restrict__ sy,
    const float* __restrict__ sz, const float* __restrict__ sw,
    unsigned long long* __restrict__ packF,
    unsigned long long* __restrict__ packB,
    int N, int M, int nbF) {
  int b = blockIdx.x;
  const float *px_, *py_, *pz_, *ox, *oy, *oz, *ow;
  unsigned long long* pack;
  int selfN, otherN;
  if (b < nbF) {  // forward: self = ref, other = transformed src
    px_ = rx; py_ = ry; pz_ = rz;
    ox = sx; oy = sy; oz = sz; ow = sw;
    pack = packF; selfN = N; otherN = M;
  } else {        // backward: self = transformed src, other = ref
    b -= nbF;
    px_ = sx; py_ = sy; pz_ = sz;
    ox = rx; oy = ry; oz = rz; ow = rw;
    pack = packB; selfN = M; otherN = N;
  }
  const int ib = b / JS, jb = b % JS;
  const int i0 = ib * (TPB * IPT) + threadIdx.x;

  float ax[IPT], ay[IPT], az[IPT], mind[IPT];
#pragma unroll
  for (int k = 0; k < IPT; k++) {
    int i = i0 + k * TPB;
    int ic = (i < selfN) ? i : (selfN - 1);  // clamp; guarded at atomic time
    ax[k] = -2.0f * px_[ic]; ay[k] = -2.0f * py_[ic]; az[k] = -2.0f * pz_[ic];
    mind[k] = INFINITY;
  }

  int chunk = (otherN + JS - 1) / JS;
  chunk = (chunk + 1) & ~1;  // even -> 8B-aligned v2f loads
  const int j0 = jb * chunk;
  const int jcount = min(chunk, otherN - j0);  // may be <= 0

#pragma unroll 4
  for (int jj = 0; jj < jcount; jj += 2) {
    v2f qx = *(const v2f*)(ox + j0 + jj);  // wave-uniform broadcast loads
    v2f qy = *(const v2f*)(oy + j0 + jj);
    v2f qz = *(const v2f*)(oz + j0 + jj);
    v2f qw = *(const v2f*)(ow + j0 + jj);
#pragma unroll
    for (int k = 0; k < IPT; k++) {
      v2f t = __builtin_elementwise_fma((v2f){ax[k], ax[k]}, qx, qw);
      t = __builtin_elementwise_fma((v2f){ay[k], ay[k]}, qy, t);
      t = __builtin_elementwise_fma((v2f){az[k], az[k]}, qz, t);
      mind[k] = fminf(fminf(t.x, t.y), mind[k]);  // v_min3_f32
    }
  }

#pragma unroll
  for (int k = 0; k < IPT; k++) {
    int i = i0 + k * TPB;
    if (i < selfN && jcount > 0) {
      unsigned long long p = ((unsigned long long)sortable(mind[k]) << 32) |
                             (unsigned int)j0;
      atomicMin(&pack[i], p);
    }
  }
}

// ---------------------------------------------------------------------------
// Kernel 3 (phase 2): ONE WAVE PER ROW. Rescan only the winning chunk
// (coalesced, lane-per-j), recompute scores with the identical fma sequence
// (bitwise-equal), find the smallest j matching the winning score bits, then
// exact distance + sigma gather + log. Lane 0 STORES terms[row] -- no
// atomics anywhere (round 4's 4096 same-address atomicAdds serialized at
// ~33 cyc each = 56 us; plain distinct-address stores have no such tail).
// ---------------------------------------------------------------------------
__global__ __launch_bounds__(256) void phase2_kernel(
    const unsigned long long* __restrict__ packF,
    const unsigned long long* __restrict__ packB,
    const float* __restrict__ rx, const float* __restrict__ ry,
    const float* __restrict__ rz, const float* __restrict__ rw,
    const float* __restrict__ sx, const float* __restrict__ sy,
    const float* __restrict__ sz, const float* __restrict__ sw,
    const float* __restrict__ ref_sigma, const float* __restrict__ src_sigma,
    float* __restrict__ terms, int N, int M) {
  const int lane = threadIdx.x & 63, wid = threadIdx.x >> 6;
  const int gw = blockIdx.x * (blockDim.x >> 6) + wid;  // global wave id
  if (gw >= N + M) return;

  const bool fwd = (gw < N);
  const int row = fwd ? gw : gw - N;
  const float *px_, *py_, *pz_, *ox, *oy, *oz, *ow, *sigA, *sigB;
  int otherN;
  const unsigned long long* pack;
  if (fwd) {
    px_ = rx; py_ = ry; pz_ = rz; ox = sx; oy = sy; oz = sz; ow = sw;
    sigA = ref_sigma; sigB = src_sigma; pack = packF; otherN = M;
  } else {
    px_ = sx; py_ = sy; pz_ = sz; ox = rx; oy = ry; oz = rz; ow = rw;
    sigA = src_sigma; sigB = ref_sigma; pack = packB; otherN = N;
  }
  const unsigned long long key = pack[row];
  const unsigned int target = (unsigned int)(key >> 32);
  const int j0 = (int)(key & 0xffffffffu);
  int chunk = (otherN + JS - 1) / JS;
  chunk = (chunk + 1) & ~1;
  const int jc = min(chunk, otherN - j0);
  const int jc2 = (jc + 1) & ~1;  // phase-1 scanned exactly [j0, j0+jc2)

  const float px = px_[row], py = py_[row], pz = pz_[row];
  const float ax = -2.0f * px, ay = -2.0f * py, az = -2.0f * pz;

  int best = 0x7fffffff;
  for (int off = lane; off < jc2; off += 64) {
    const int j = j0 + off;
    float t = fmaf(ax, ox[j], ow[j]);
    t = fmaf(ay, oy[j], t);
    t = fmaf(az, oz[j], t);
    if (sortable(t) == target) best = min(best, j);
  }
#pragma unroll
  for (int o = 32; o > 0; o >>= 1) best = min(best, __shfl_xor(best, o, 64));

  if (lane == 0) {
    const float dx = px - ox[best], dy = py - oy[best], dz = pz - oz[best];
    const float d = sqrtf(dx * dx + dy * dy + dz * dz);
    const float sigma = 0.5f * (sigA[row] + sigB[best]);
    terms[gw] = (logf(sigma) + d / sigma) *
                (fwd ? 1.0f / (float)N : 1.0f / (float)M);
  }
}

// ---------------------------------------------------------------------------
// Kernel 4: single-block deterministic sum of the per-row terms -> d_out.
// ---------------------------------------------------------------------------
__global__ __launch_bounds__(256) void reduce_kernel(
    const float* __restrict__ terms, float* __restrict__ out, int total) {
  float s = 0.f;
  for (int i = threadIdx.x; i < total; i += 256) s += terms[i];
#pragma unroll
  for (int o = 32; o > 0; o >>= 1) s += __shfl_down(s, o, 64);
  __shared__ float wsum[4];
  const int lane = threadIdx.x & 63, wid = threadIdx.x >> 6;
  if (lane == 0) wsum[wid] = s;
  __syncthreads();
  if (threadIdx.x == 0) out[0] = wsum[0] + wsum[1] + wsum[2] + wsum[3];
}

extern "C" void kernel_launch(void* const* d_in, const int* in_sizes, int n_in,
                              void* d_out, int out_size, void* d_ws,
                              size_t ws_size, hipStream_t stream) {
  const float* ref_kpts  = (const float*)d_in[0];
  const float* src_kpts  = (const float*)d_in[1];
  const float* gt        = (const float*)d_in[2];
  const float* ref_sigma = (const float*)d_in[3];
  const float* src_sigma = (const float*)d_in[4];
  float* out = (float*)d_out;

  const int N = in_sizes[0] / 3;
  const int M = in_sizes[1] / 3;

  // workspace layout (SoA, each array padded +1 sentinel, stride rounded to
  // 4 floats so every array base stays 16B-aligned)
  const int NP = (N + 1 + 3) & ~3;
  const int MP = (M + 1 + 3) & ~3;
  float* f = (float*)d_ws;
  float* rx = f;            float* ry = f + NP;
  float* rz = f + 2 * NP;   float* rw = f + 3 * NP;
  float* sx = f + 4 * NP;           float* sy = f + 4 * NP + MP;
  float* sz = f + 4 * NP + 2 * MP;  float* sw = f + 4 * NP + 3 * MP;
  unsigned long long* packF = (unsigned long long*)(f + 4 * NP + 4 * MP);
  unsigned long long* packB = packF + N;
  float* terms = (float*)(packB + M);  // N + M floats

  int nPts = (N > M) ? N : M;
  setup_kernel<<<(nPts + 255) / 256, 256, 0, stream>>>(
      ref_kpts, src_kpts, gt, rx, ry, rz, rw, sx, sy, sz, sw, packF, packB,
      N, M);

  const int ibF = (N + TPB * IPT - 1) / (TPB * IPT);  // row-blocks (forward)
  const int ibB = (M + TPB * IPT - 1) / (TPB * IPT);  // row-blocks (backward)
  const int nbF = ibF * JS;
  const int nbB = ibB * JS;
  pairs_kernel<<<nbF + nbB, TPB, 0, stream>>>(rx, ry, rz, rw, sx, sy, sz, sw,
                                              packF, packB, N, M, nbF);

  const int waves = N + M;   // one wave per row
  const int wpb = 256 / 64;  // waves per block
  phase2_kernel<<<(waves + wpb - 1) / wpb, 256, 0, stream>>>(
      packF, packB, rx, ry, rz, rw, sx, sy, sz, sw, ref_sigma, src_sigma,
      terms, N, M);

  reduce_kernel<<<1, 256, 0, stream>>>(terms, out, N + M);
}

// Round 6
// 95.759 us; speedup vs baseline: 1.3549x; 1.0209x over previous
//
#include <hip/hip_runtime.h>
#include <math.h>

typedef float v2f __attribute__((ext_vector_type(2)));

#define TPB 256   // threads per block
#define IPT 4     // "self" rows per thread (registers)
#define JS  64    // j-slices per direction (split-K over the other cloud)
#define RPW 16    // rows per wave in the finalize kernel

// ---------------------------------------------------------------------------
// Kernel 1 (fused setup): transform src, repack BOTH clouds as SoA
// (x[], y[], z[], w[]=|v|^2), init pack arrays to u64-max, zero d_out,
// +INF sentinel pads for the 2-wide tail reads.
// ---------------------------------------------------------------------------
__global__ __launch_bounds__(256) void setup_kernel(
    const float* __restrict__ ref, const float* __restrict__ src,
    const float* __restrict__ T,
    float* __restrict__ rx, float* __restrict__ ry, float* __restrict__ rz,
    float* __restrict__ rw,
    float* __restrict__ sx, float* __restrict__ sy, float* __restrict__ sz,
    float* __restrict__ sw,
    unsigned long long* __restrict__ packF,
    unsigned long long* __restrict__ packB,
    float* __restrict__ out, int N, int M) {
  int i = blockIdx.x * blockDim.x + threadIdx.x;
  if (i < M) {
    float x = src[3 * i], y = src[3 * i + 1], z = src[3 * i + 2];
    float tx = T[0] * x + T[1] * y + T[2]  * z + T[3];
    float ty = T[4] * x + T[5] * y + T[6]  * z + T[7];
    float tz = T[8] * x + T[9] * y + T[10] * z + T[11];
    sx[i] = tx; sy[i] = ty; sz[i] = tz;
    sw[i] = tx * tx + ty * ty + tz * tz;
    packB[i] = ~0ull;
  }
  if (i < N) {
    float x = ref[3 * i], y = ref[3 * i + 1], z = ref[3 * i + 2];
    rx[i] = x; ry[i] = y; rz[i] = z;
    rw[i] = x * x + y * y + z * z;
    packF[i] = ~0ull;
  }
  if (i == 0) {
    out[0] = 0.0f;  // finalize accumulates via atomicAdd
    rx[N] = 0.f; ry[N] = 0.f; rz[N] = 0.f; rw[N] = INFINITY;  // pad sentinel
    sx[M] = 0.f; sy[M] = 0.f; sz[M] = 0.f; sw[M] = INFINITY;  // pad sentinel
  }
}

__device__ __forceinline__ unsigned int sortable(float f) {
  unsigned int u = __float_as_uint(f);
  return u ^ ((unsigned int)((int)u >> 31) | 0x80000000u);
}

// ---------------------------------------------------------------------------
// Kernel 2 (phase 1): per-(row, chunk) MIN of score_j = |q_j|^2 - 2 p.q_j
// -- value only, NO index tracking:
//   per 2 j's per row: 3 v_pk_fma_f32 + 1 v_min3_f32 = 2.0 VALU/pair.
// Partials merged via packed-u64 atomicMin (distinct address per row):
//   key = (sortable score bits << 32) | chunk_base_j0
// Ties pick the smallest chunk -> with finalize's smallest-matching-j scan
// this reproduces jnp.argmin first-occurrence semantics exactly.
// ---------------------------------------------------------------------------
__global__ __launch_bounds__(TPB) void pairs_kernel(
    const float* __restrict__ rx, const float* __restrict__ ry,
    const float* __restrict__ rz, const float* __restrict__ rw,
    const float* __restrict__ sx, const float* __restrict__ sy,
    const float* __restrict__ sz, const float* __restrict__ sw,
    unsigned long long* __restrict__ packF,
    unsigned long long* __restrict__ packB,
    int N, int M, int nbF) {
  int b = blockIdx.x;
  const float *px_, *py_, *pz_, *ox, *oy, *oz, *ow;
  unsigned long long* pack;
  int selfN, otherN;
  if (b < nbF) {  // forward: self = ref, other = transformed src
    px_ = rx; py_ = ry; pz_ = rz;
    ox = sx; oy = sy; oz = sz; ow = sw;
    pack = packF; selfN = N; otherN = M;
  } else {        // backward: self = transformed src, other = ref
    b -= nbF;
    px_ = sx; py_ = sy; pz_ = sz;
    ox = rx; oy = ry; oz = rz; ow = rw;
    pack = packB; selfN = M; otherN = N;
  }
  const int ib = b / JS, jb = b % JS;
  const int i0 = ib * (TPB * IPT) + threadIdx.x;

  float ax[IPT], ay[IPT], az[IPT], mind[IPT];
#pragma unroll
  for (int k = 0; k < IPT; k++) {
    int i = i0 + k * TPB;
    int ic = (i < selfN) ? i : (selfN - 1);  // clamp; guarded at atomic time
    ax[k] = -2.0f * px_[ic]; ay[k] = -2.0f * py_[ic]; az[k] = -2.0f * pz_[ic];
    mind[k] = INFINITY;
  }

  int chunk = (otherN + JS - 1) / JS;
  chunk = (chunk + 1) & ~1;  // even -> 8B-aligned v2f loads
  const int j0 = jb * chunk;
  const int jcount = min(chunk, otherN - j0);  // may be <= 0

#pragma unroll 4
  for (int jj = 0; jj < jcount; jj += 2) {
    v2f qx = *(const v2f*)(ox + j0 + jj);  // wave-uniform broadcast loads
    v2f qy = *(const v2f*)(oy + j0 + jj);
    v2f qz = *(const v2f*)(oz + j0 + jj);
    v2f qw = *(const v2f*)(ow + j0 + jj);
#pragma unroll
    for (int k = 0; k < IPT; k++) {
      v2f t = __builtin_elementwise_fma((v2f){ax[k], ax[k]}, qx, qw);
      t = __builtin_elementwise_fma((v2f){ay[k], ay[k]}, qy, t);
      t = __builtin_elementwise_fma((v2f){az[k], az[k]}, qz, t);
      mind[k] = fminf(fminf(t.x, t.y), mind[k]);  // v_min3_f32
    }
  }

#pragma unroll
  for (int k = 0; k < IPT; k++) {
    int i = i0 + k * TPB;
    if (i < selfN && jcount > 0) {
      unsigned long long p = ((unsigned long long)sortable(mind[k]) << 32) |
                             (unsigned int)j0;
      atomicMin(&pack[i], p);
    }
  }
}

// ---------------------------------------------------------------------------
// Kernel 3 (phase 2 + reduction, fused): each wave handles RPW rows
// serially. Per row: rescan only the winning chunk (coalesced lane-per-j,
// bitwise-identical fma sequence), butterfly-min the smallest matching j,
// compute the term (redundantly on all lanes -- broadcast gathers), and
// accumulate. Block LDS sum -> ONE atomicAdd per block (256 total, arriving
// staggered -- no round-4-style serialized tail).
// ---------------------------------------------------------------------------
__global__ __launch_bounds__(256) void finalize_kernel(
    const unsigned long long* __restrict__ packF,
    const unsigned long long* __restrict__ packB,
    const float* __restrict__ rx, const float* __restrict__ ry,
    const float* __restrict__ rz, const float* __restrict__ rw,
    const float* __restrict__ sx, const float* __restrict__ sy,
    const float* __restrict__ sz, const float* __restrict__ sw,
    const float* __restrict__ ref_sigma, const float* __restrict__ src_sigma,
    float* __restrict__ out, int N, int M) {
  const int lane = threadIdx.x & 63, wid = threadIdx.x >> 6;
  const int gw = blockIdx.x * (blockDim.x >> 6) + wid;  // global wave id
  const int base = gw * RPW;

  float sum = 0.f;
  for (int r = 0; r < RPW; r++) {
    const int rowg = base + r;
    if (rowg >= N + M) break;
    const bool fwd = (rowg < N);
    const int row = fwd ? rowg : rowg - N;
    const float *px_, *py_, *pz_, *ox, *oy, *oz, *ow, *sigA, *sigB;
    int otherN;
    const unsigned long long* pack;
    if (fwd) {
      px_ = rx; py_ = ry; pz_ = rz; ox = sx; oy = sy; oz = sz; ow = sw;
      sigA = ref_sigma; sigB = src_sigma; pack = packF; otherN = M;
    } else {
      px_ = sx; py_ = sy; pz_ = sz; ox = rx; oy = ry; oz = rz; ow = rw;
      sigA = src_sigma; sigB = ref_sigma; pack = packB; otherN = N;
    }
    const unsigned long long key = pack[row];
    const unsigned int target = (unsigned int)(key >> 32);
    const int j0 = (int)(key & 0xffffffffu);
    int chunk = (otherN + JS - 1) / JS;
    chunk = (chunk + 1) & ~1;
    const int jc = min(chunk, otherN - j0);
    const int jc2 = (jc + 1) & ~1;  // phase-1 scanned exactly [j0, j0+jc2)

    const float px = px_[row], py = py_[row], pz = pz_[row];
    const float ax = -2.0f * px, ay = -2.0f * py, az = -2.0f * pz;

    int best = 0x7fffffff;
    for (int off = lane; off < jc2; off += 64) {
      const int j = j0 + off;
      float t = fmaf(ax, ox[j], ow[j]);
      t = fmaf(ay, oy[j], t);
      t = fmaf(az, oz[j], t);
      if (sortable(t) == target) best = min(best, j);
    }
#pragma unroll
    for (int o = 32; o > 0; o >>= 1)
      best = min(best, __shfl_xor(best, o, 64));
    // all lanes now hold the winning j; compute the term redundantly
    const float dx = px - ox[best], dy = py - oy[best], dz = pz - oz[best];
    const float d = sqrtf(dx * dx + dy * dy + dz * dz);
    const float sigma = 0.5f * (sigA[row] + sigB[best]);
    sum += (logf(sigma) + d / sigma) *
           (fwd ? 1.0f / (float)N : 1.0f / (float)M);
  }

  __shared__ float wsum[4];
  if (lane == 0) wsum[wid] = sum;
  __syncthreads();
  if (threadIdx.x == 0)
    atomicAdd(out, wsum[0] + wsum[1] + wsum[2] + wsum[3]);
}

extern "C" void kernel_launch(void* const* d_in, const int* in_sizes, int n_in,
                              void* d_out, int out_size, void* d_ws,
                              size_t ws_size, hipStream_t stream) {
  const float* ref_kpts  = (const float*)d_in[0];
  const float* src_kpts  = (const float*)d_in[1];
  const float* gt        = (const float*)d_in[2];
  const float* ref_sigma = (const float*)d_in[3];
  const float* src_sigma = (const float*)d_in[4];
  float* out = (float*)d_out;

  const int N = in_sizes[0] / 3;
  const int M = in_sizes[1] / 3;

  // workspace layout (SoA, each array padded +1 sentinel, stride rounded to
  // 4 floats so every array base stays 16B-aligned)
  const int NP = (N + 1 + 3) & ~3;
  const int MP = (M + 1 + 3) & ~3;
  float* f = (float*)d_ws;
  float* rx = f;            float* ry = f + NP;
  float* rz = f + 2 * NP;   float* rw = f + 3 * NP;
  float* sx = f + 4 * NP;           float* sy = f + 4 * NP + MP;
  float* sz = f + 4 * NP + 2 * MP;  float* sw = f + 4 * NP + 3 * MP;
  unsigned long long* packF = (unsigned long long*)(f + 4 * NP + 4 * MP);
  unsigned long long* packB = packF + N;

  int nPts = (N > M) ? N : M;
  setup_kernel<<<(nPts + 255) / 256, 256, 0, stream>>>(
      ref_kpts, src_kpts, gt, rx, ry, rz, rw, sx, sy, sz, sw, packF, packB,
      out, N, M);

  const int ibF = (N + TPB * IPT - 1) / (TPB * IPT);  // row-blocks (forward)
  const int ibB = (M + TPB * IPT - 1) / (TPB * IPT);  // row-blocks (backward)
  const int nbF = ibF * JS;
  const int nbB = ibB * JS;
  pairs_kernel<<<nbF + nbB, TPB, 0, stream>>>(rx, ry, rz, rw, sx, sy, sz, sw,
                                              packF, packB, N, M, nbF);

  const int waves = (N + M + RPW - 1) / RPW;  // one wave per RPW rows
  const int wpb = 256 / 64;                   // waves per block
  finalize_kernel<<<(waves + wpb - 1) / wpb, 256, 0, stream>>>(
      packF, packB, rx, ry, rz, rw, sx, sy, sz, sw, ref_sigma, src_sigma,
      out, N, M);
}

// Round 7
// 86.525 us; speedup vs baseline: 1.4995x; 1.1067x over previous
//
#include <hip/hip_runtime.h>
#include <math.h>

typedef float v2f __attribute__((ext_vector_type(2)));

#define TPB 256   // threads per block
#define IPT 4     // "self" rows per thread (registers)
#define JS  64    // j-slices per direction (split-K over the other cloud)

// ---------------------------------------------------------------------------
// Kernel 1 (fused setup): transform src, repack BOTH clouds as SoA
// (x[], y[], z[], w[]=|v|^2), init pack arrays to u64-max, zero d_out,
// +INF sentinel pads for the 2-wide tail reads.
// ---------------------------------------------------------------------------
__global__ __launch_bounds__(256) void setup_kernel(
    const float* __restrict__ ref, const float* __restrict__ src,
    const float* __restrict__ T,
    float* __restrict__ rx, float* __restrict__ ry, float* __restrict__ rz,
    float* __restrict__ rw,
    float* __restrict__ sx, float* __restrict__ sy, float* __restrict__ sz,
    float* __restrict__ sw,
    unsigned long long* __restrict__ packF,
    unsigned long long* __restrict__ packB,
    float* __restrict__ out, int N, int M) {
  int i = blockIdx.x * blockDim.x + threadIdx.x;
  if (i < M) {
    float x = src[3 * i], y = src[3 * i + 1], z = src[3 * i + 2];
    float tx = T[0] * x + T[1] * y + T[2]  * z + T[3];
    float ty = T[4] * x + T[5] * y + T[6]  * z + T[7];
    float tz = T[8] * x + T[9] * y + T[10] * z + T[11];
    sx[i] = tx; sy[i] = ty; sz[i] = tz;
    sw[i] = tx * tx + ty * ty + tz * tz;
    packB[i] = ~0ull;
  }
  if (i < N) {
    float x = ref[3 * i], y = ref[3 * i + 1], z = ref[3 * i + 2];
    rx[i] = x; ry[i] = y; rz[i] = z;
    rw[i] = x * x + y * y + z * z;
    packF[i] = ~0ull;
  }
  if (i == 0) {
    out[0] = 0.0f;  // finalize accumulates via atomicAdd
    rx[N] = 0.f; ry[N] = 0.f; rz[N] = 0.f; rw[N] = INFINITY;  // pad sentinel
    sx[M] = 0.f; sy[M] = 0.f; sz[M] = 0.f; sw[M] = INFINITY;  // pad sentinel
  }
}

__device__ __forceinline__ unsigned int sortable(float f) {
  unsigned int u = __float_as_uint(f);
  return u ^ ((unsigned int)((int)u >> 31) | 0x80000000u);
}

// ---------------------------------------------------------------------------
// Kernel 2: fused bidirectional argmin over score_j = |q_j|^2 - 2 p.q_j
// (equal-argmin to squared distance; |p|^2 is row-constant). Index tracked
// INLINE (r3 structure -- measured best):
//   two j's per step: 3 v_pk_fma_f32 + 2x(cmp+2 cndmask) = 4.5 VALU/pair.
// Sequential strict-< selects preserve first-occurrence (smallest j) ==
// jnp.argmin. Split-K partials merged via sortable-key packed-u64 atomicMin
// (distinct address per row; ties -> smallest j since key low32 = j).
// ---------------------------------------------------------------------------
__global__ __launch_bounds__(TPB) void pairs_kernel(
    const float* __restrict__ rx, const float* __restrict__ ry,
    const float* __restrict__ rz, const float* __restrict__ rw,
    const float* __restrict__ sx, const float* __restrict__ sy,
    const float* __restrict__ sz, const float* __restrict__ sw,
    unsigned long long* __restrict__ packF,
    unsigned long long* __restrict__ packB,
    int N, int M, int nbF) {
  int b = blockIdx.x;
  const float *px_, *py_, *pz_, *ox, *oy, *oz, *ow;
  unsigned long long* pack;
  int selfN, otherN;
  if (b < nbF) {  // forward: self = ref, other = transformed src
    px_ = rx; py_ = ry; pz_ = rz;
    ox = sx; oy = sy; oz = sz; ow = sw;
    pack = packF; selfN = N; otherN = M;
  } else {        // backward: self = transformed src, other = ref
    b -= nbF;
    px_ = sx; py_ = sy; pz_ = sz;
    ox = rx; oy = ry; oz = rz; ow = rw;
    pack = packB; selfN = M; otherN = N;
  }
  const int ib = b / JS, jb = b % JS;
  const int i0 = ib * (TPB * IPT) + threadIdx.x;

  float ax[IPT], ay[IPT], az[IPT], mind[IPT];
  int mini[IPT];
#pragma unroll
  for (int k = 0; k < IPT; k++) {
    int i = i0 + k * TPB;
    int ic = (i < selfN) ? i : (selfN - 1);  // clamp; guarded at atomic time
    ax[k] = -2.0f * px_[ic]; ay[k] = -2.0f * py_[ic]; az[k] = -2.0f * pz_[ic];
    mind[k] = INFINITY; mini[k] = 0;
  }

  int chunk = (otherN + JS - 1) / JS;
  chunk = (chunk + 1) & ~1;  // even -> 8B-aligned v2f loads
  const int j0 = jb * chunk;
  const int jcount = min(chunk, otherN - j0);  // may be <= 0

#pragma unroll 4
  for (int jj = 0; jj < jcount; jj += 2) {
    v2f qx = *(const v2f*)(ox + j0 + jj);  // wave-uniform broadcast loads
    v2f qy = *(const v2f*)(oy + j0 + jj);
    v2f qz = *(const v2f*)(oz + j0 + jj);
    v2f qw = *(const v2f*)(ow + j0 + jj);
#pragma unroll
    for (int k = 0; k < IPT; k++) {
      v2f t = __builtin_elementwise_fma((v2f){ax[k], ax[k]}, qx, qw);
      t = __builtin_elementwise_fma((v2f){ay[k], ay[k]}, qy, t);
      t = __builtin_elementwise_fma((v2f){az[k], az[k]}, qz, t);
      if (t.x < mind[k]) { mind[k] = t.x; mini[k] = jj; }
      if (t.y < mind[k]) { mind[k] = t.y; mini[k] = jj + 1; }
    }
  }

#pragma unroll
  for (int k = 0; k < IPT; k++) {
    int i = i0 + k * TPB;
    if (i < selfN && jcount > 0) {
      unsigned long long p = ((unsigned long long)sortable(mind[k]) << 32) |
                             (unsigned int)(j0 + mini[k]);
      atomicMin(&pack[i], p);
    }
  }
}

// ---------------------------------------------------------------------------
// Kernel 3: trivial epilogue, thread-per-row (no rescan -- index is in the
// pack key). Exact fp32 distance recomputed from the winning index, sigma
// gather, log, mean; wave+LDS block reduce; 64 staggered atomicAdds total.
// ---------------------------------------------------------------------------
__global__ __launch_bounds__(256) void finalize_kernel(
    const unsigned long long* __restrict__ packF,
    const unsigned long long* __restrict__ packB,
    const float* __restrict__ rx, const float* __restrict__ ry,
    const float* __restrict__ rz,
    const float* __restrict__ sx, const float* __restrict__ sy,
    const float* __restrict__ sz,
    const float* __restrict__ ref_sigma, const float* __restrict__ src_sigma,
    float* __restrict__ out, int N, int M) {
  int gid = blockIdx.x * blockDim.x + threadIdx.x;
  float term = 0.f;
  if (gid < N) {
    int idx = (int)(packF[gid] & 0xffffffffu);
    float dx = rx[gid] - sx[idx], dy = ry[gid] - sy[idx],
          dz = rz[gid] - sz[idx];
    float d = sqrtf(dx * dx + dy * dy + dz * dz);
    float sigma = 0.5f * (ref_sigma[gid] + src_sigma[idx]);
    term = (logf(sigma) + d / sigma) * (1.0f / (float)N);
  } else if (gid < N + M) {
    int j = gid - N;
    int idx = (int)(packB[j] & 0xffffffffu);
    float dx = sx[j] - rx[idx], dy = sy[j] - ry[idx], dz = sz[j] - rz[idx];
    float d = sqrtf(dx * dx + dy * dy + dz * dz);
    float sigma = 0.5f * (src_sigma[j] + ref_sigma[idx]);
    term = (logf(sigma) + d / sigma) * (1.0f / (float)M);
  }
#pragma unroll
  for (int o = 32; o > 0; o >>= 1) term += __shfl_down(term, o, 64);
  __shared__ float wsum[4];
  const int lane = threadIdx.x & 63, wid = threadIdx.x >> 6;
  if (lane == 0) wsum[wid] = term;
  __syncthreads();
  if (threadIdx.x == 0)
    atomicAdd(out, wsum[0] + wsum[1] + wsum[2] + wsum[3]);
}

extern "C" void kernel_launch(void* const* d_in, const int* in_sizes, int n_in,
                              void* d_out, int out_size, void* d_ws,
                              size_t ws_size, hipStream_t stream) {
  const float* ref_kpts  = (const float*)d_in[0];
  const float* src_kpts  = (const float*)d_in[1];
  const float* gt        = (const float*)d_in[2];
  const float* ref_sigma = (const float*)d_in[3];
  const float* src_sigma = (const float*)d_in[4];
  float* out = (float*)d_out;

  const int N = in_sizes[0] / 3;
  const int M = in_sizes[1] / 3;

  // workspace layout (SoA, each array padded +1 sentinel, stride rounded to
  // 4 floats so every array base stays 16B-aligned)
  const int NP = (N + 1 + 3) & ~3;
  const int MP = (M + 1 + 3) & ~3;
  float* f = (float*)d_ws;
  float* rx = f;            float* ry = f + NP;
  float* rz = f + 2 * NP;   float* rw = f + 3 * NP;
  float* sx = f + 4 * NP;           float* sy = f + 4 * NP + MP;
  float* sz = f + 4 * NP + 2 * MP;  float* sw = f + 4 * NP + 3 * MP;
  unsigned long long* packF = (unsigned long long*)(f + 4 * NP + 4 * MP);
  unsigned long long* packB = packF + N;

  int nPts = (N > M) ? N : M;
  setup_kernel<<<(nPts + 255) / 256, 256, 0, stream>>>(
      ref_kpts, src_kpts, gt, rx, ry, rz, rw, sx, sy, sz, sw, packF, packB,
      out, N, M);

  const int ibF = (N + TPB * IPT - 1) / (TPB * IPT);  // row-blocks (forward)
  const int ibB = (M + TPB * IPT - 1) / (TPB * IPT);  // row-blocks (backward)
  const int nbF = ibF * JS;
  const int nbB = ibB * JS;
  pairs_kernel<<<nbF + nbB, TPB, 0, stream>>>(rx, ry, rz, rw, sx, sy, sz, sw,
                                              packF, packB, N, M, nbF);

  finalize_kernel<<<(N + M + 255) / 256, 256, 0, stream>>>(
      packF, packB, rx, ry, rz, sx, sy, sz, ref_sigma, src_sigma, out, N, M);
}